// Round 14
// baseline (22.772 us; speedup 1.0000x reference)
//
#include <hip/hip_runtime.h>
#include <hip/hip_fp16.h>

#define N_REL 201   // NUM_RELS + 1 (PAD row 200 is all-zero)
#define N_TGT 200   // target_rels < 200
#define SEM 32      // SEM_DIM
#define KNEI 20     // K neighbors
#define PSTRIDE 40  // halfs per P row (80 B -> uniform spread over all 8 quad-groups)

typedef float floatx4 __attribute__((ext_vector_type(4)));

// Workspace: [0,80400) __half St[200][201]; [80400,+32160) __half P[402][40]
#define ST_BYTES 80400                 // 16-aligned (16*5025)
#define P_HALFS (2 * N_REL * PSTRIDE)  // 16080
#define P_U4 (P_HALFS * 2 / 16)        // 2010

#define EMB_STRIDE 68   // floats/row: 16B-aligned, dword-stride 17 (odd)
#define WL_STRIDE 132   // floats/row: 16B-aligned, dword-stride 33 (odd)

// ---------------------------------------------------------------------------
// Kernel 1: WARM + BUILD.  Blocks [0, nbf): prefetch fuse-block-p's exact
// input bytes (idx/feat/target) at streaming BW — same round-robin XCD as
// fuse block p, so lines land in the RIGHT per-XCD L2. Blocks [nbf, nbf+201):
// the r13 table build (St = emb.emb^T fp16; P = emb.W^T + bias/2 fp16).
// ---------------------------------------------------------------------------
__global__ __launch_bounds__(256) void warm_build_kernel(
    const int* __restrict__ out_nei, const int* __restrict__ in_nei,
    const int* __restrict__ target,
    const float* __restrict__ rel_emb,   // [201][64]
    const float* __restrict__ w,         // [32][128]
    const float* __restrict__ bias,      // [32]
    const float* __restrict__ feat,      // [N][32]
    __half* __restrict__ St,             // [200][201] transposed
    __half* __restrict__ P,              // [402][PSTRIDE]
    int n_nodes, int nbf)
{
  const int b = blockIdx.x;
  const int t = threadIdx.x;

  if (b < nbf) {
    // ---- prefetch: exactly the bytes fuse block b will read ----
    const int n0 = b * 32;
    const int nn = min(32, n_nodes - n0);
    if (nn <= 0) return;
    const int c_o = nn * 5;            // uint4s of out_nei (80 B/node)
    const int c_f = nn * 8;            // uint4s of feat (128 B/node)
    const int c_t = (nn + 3) >> 2;     // uint4s of target
    const uint4* o4 = (const uint4*)(out_nei + (size_t)n0 * KNEI);
    const uint4* i4 = (const uint4*)(in_nei  + (size_t)n0 * KNEI);
    const uint4* f4 = (const uint4*)(feat    + (size_t)n0 * SEM);
    const uint4* t4 = (const uint4*)(target  + n0);
    const int tot = 2 * c_o + c_f + c_t;   // 584 for full blocks
    for (int e = t; e < tot; e += 256) {
      uint4 v;
      if (e < c_o)                 v = o4[e];
      else if (e < 2 * c_o)        v = i4[e - c_o];
      else if (e < 2 * c_o + c_f)  v = f4[e - 2 * c_o];
      else                         v = t4[e - 2 * c_o - c_f];
      asm volatile("" :: "v"(v.x), "v"(v.y), "v"(v.z), "v"(v.w));  // keep live
    }
    return;
  }

  // ---- build part (r13-identical, block i = b - nbf) ----
  __shared__ __align__(16) float embL[N_REL * EMB_STRIDE];
  __shared__ __align__(16) float wL[SEM * WL_STRIDE];
  for (int e = t; e < N_REL * 16; e += 256) {
    const int r = e >> 4, s = e & 15;
    *(float4*)&embL[r * EMB_STRIDE + s * 4] = ((const float4*)rel_emb)[e];
  }
  for (int e = t; e < SEM * 32; e += 256) {
    const int r = e >> 5, s = e & 31;
    *(float4*)&wL[r * WL_STRIDE + s * 4] = ((const float4*)w)[e];
  }
  __syncthreads();

  const int i = b - nbf;  // 0..200 (idx dimension)
  const float4* __restrict__ ri = (const float4*)&embL[i * EMB_STRIDE];
  for (int jj = t; jj < N_TGT; jj += 256) {
    const float4* __restrict__ rj = (const float4*)&embL[jj * EMB_STRIDE];
    float acc = 0.f;
#pragma unroll
    for (int d = 0; d < 16; ++d) {
      const float4 a = ri[d], bb = rj[d];
      acc = fmaf(a.x, bb.x, acc);
      acc = fmaf(a.y, bb.y, acc);
      acc = fmaf(a.z, bb.z, acc);
      acc = fmaf(a.w, bb.w, acc);
    }
    St[jj * N_REL + i] = __float2half(acc);
  }
  if (t < 64) {
    const int hh = t >> 5, jj = t & 31;
    const float4* __restrict__ rw = (const float4*)&wL[jj * WL_STRIDE + hh * 64];
    float acc = 0.5f * bias[jj];
#pragma unroll
    for (int d = 0; d < 16; ++d) {
      const float4 a = ri[d], bb = rw[d];
      acc = fmaf(a.x, bb.x, acc);
      acc = fmaf(a.y, bb.y, acc);
      acc = fmaf(a.z, bb.z, acc);
      acc = fmaf(a.w, bb.w, acc);
    }
    P[(hh * N_REL + i) * PSTRIDE + jj] = __float2half(acc);
  }
}

// ---------------------------------------------------------------------------
// Kernel 2: r13-identical best fuse (8 lanes/node, 256-thr, uint4 idx loads,
// plain feat loads, NT out stores).
// ---------------------------------------------------------------------------
__global__ __launch_bounds__(256, 4) void fuse_kernel(
    const int* __restrict__ out_nei, const int* __restrict__ in_nei,
    const int* __restrict__ target, const float* __restrict__ feat,
    const __half* __restrict__ St, const __half* __restrict__ Pg,
    float* __restrict__ out, int n_nodes)
{
  __shared__ __align__(16) __half P_l[P_HALFS];    // 32160 B
  const int t = threadIdx.x;
  const int gid = blockIdx.x * 256 + t;
  const int n = gid >> 3;
  const int sub = t & 7;
  const int dir = sub >> 2;   // 0 = out, 1 = in
  const int q = sub & 3;      // 8-dim slice / k-chunk
  const bool active = (n < n_nodes);
  const int* __restrict__ nei = dir ? in_nei : out_nei;

  // ---- phase 1: issue all input loads (latency hides under P staging) ----
  int tgt = 0, ex = 0;
  uint4 c4 = {0, 0, 0, 0};
  floatx4 f0, f1;
  if (active) {
    tgt = target[n];
    c4 = *(const uint4*)(nei + (size_t)n * KNEI + 4 * q);
    ex = nei[(size_t)n * KNEI + 16 + q];
    if (dir == 0) {
      const floatx4* fr = (const floatx4*)(feat + (size_t)n * SEM + q * 8);
      f0 = fr[0];
      f1 = fr[1];
    }
  }

  // ---- phase 2: stage P into LDS ----
  {
    const uint4* p4 = (const uint4*)Pg;
    uint4* pl = (uint4*)P_l;
    for (int e = t; e < P_U4; e += 256) pl[e] = p4[e];
  }
  __syncthreads();
  if (!active) return;

  // ---- phase 3: S gathers (St row tgt, hot in L1/L2) ----
  const __half* __restrict__ srow = St + (size_t)tgt * N_REL;
  float ev[5];
  ev[0] = __half2float(srow[c4.x]);
  ev[1] = __half2float(srow[c4.y]);
  ev[2] = __half2float(srow[c4.z]);
  ev[3] = __half2float(srow[c4.w]);
  ev[4] = __half2float(srow[ex]);

  // ---- softmax with max-subtraction (self-neighbor scores ~ ||emb||^2) ----
  float mx = fmaxf(fmaxf(fmaxf(ev[0], ev[1]), fmaxf(ev[2], ev[3])), ev[4]);
  mx = fmaxf(mx, __shfl_xor(mx, 1, 64));
  mx = fmaxf(mx, __shfl_xor(mx, 2, 64));
  float e5[5], s = 0.f;
#pragma unroll
  for (int i = 0; i < 5; ++i) { e5[i] = __expf(ev[i] - mx); s += e5[i]; }
  s += __shfl_xor(s, 1, 64);
  s += __shfl_xor(s, 2, 64);
  const float inv = __fdividef(1.f, s);

  // ---- pack {idx | w_fp16}; all-gather within the dir quad ----
  const int ia[5] = {(int)c4.x, (int)c4.y, (int)c4.z, (int)c4.w, ex};
  unsigned int pk[20];
#pragma unroll
  for (int i = 0; i < 5; ++i) {
    const __half hw = __float2half(e5[i] * inv);
    pk[i] = ((unsigned int)ia[i] << 16) | (unsigned int)__half_as_ushort(hw);
  }
#pragma unroll
  for (int i = 0; i < 5; ++i) pk[5 + i] = __shfl_xor(pk[i], 1, 64);
#pragma unroll
  for (int i = 0; i < 10; ++i) pk[10 + i] = __shfl_xor(pk[i], 2, 64);

  // ---- aggregate 20 rows, own 8-dim slice (1 b128 per row, BW-floor) ----
  __half2 acc[4];
#pragma unroll
  for (int m = 0; m < 4; ++m) acc[m] = __float2half2_rn(0.f);
  const int dbase = dir * (N_REL * PSTRIDE) + q * 8;
#pragma unroll
  for (int i = 0; i < 20; ++i) {
    const int idx = (int)(pk[i] >> 16);
    const unsigned int lo = pk[i] & 0xFFFFu;
    const unsigned int dd = lo | (lo << 16);
    const __half2 a2 = *(const __half2*)&dd;
    const uint4 qv = *(const uint4*)&P_l[dbase + idx * PSTRIDE];
    acc[0] = __hfma2(a2, *(const __half2*)&qv.x, acc[0]);
    acc[1] = __hfma2(a2, *(const __half2*)&qv.y, acc[1]);
    acc[2] = __hfma2(a2, *(const __half2*)&qv.z, acc[2]);
    acc[3] = __hfma2(a2, *(const __half2*)&qv.w, acc[3]);
  }

  // ---- combine directions: partner lane = lane ^ 4 ----
#pragma unroll
  for (int m = 0; m < 4; ++m) {
    const unsigned int u = *(const unsigned int*)&acc[m];
    const unsigned int v = __shfl_xor(u, 4, 64);
    acc[m] = __hadd2(acc[m], *(const __half2*)&v);
  }

  // ---- write: lanes 0-3 -> feat slice, lanes 4-7 -> sigmoid slice (NT) ----
  float* orow = out + (size_t)n * 64 + sub * 8;
  if (dir == 0) {
    __builtin_nontemporal_store(f0, (floatx4*)orow);
    __builtin_nontemporal_store(f1, (floatx4*)orow + 1);
  } else {
    float tv[8];
#pragma unroll
    for (int m = 0; m < 4; ++m) {
      tv[2 * m]     = __low2float(acc[m]);
      tv[2 * m + 1] = __high2float(acc[m]);
    }
    floatx4 s0, s1;
    s0.x = __fdividef(1.f, 1.f + __expf(-tv[0]));
    s0.y = __fdividef(1.f, 1.f + __expf(-tv[1]));
    s0.z = __fdividef(1.f, 1.f + __expf(-tv[2]));
    s0.w = __fdividef(1.f, 1.f + __expf(-tv[3]));
    s1.x = __fdividef(1.f, 1.f + __expf(-tv[4]));
    s1.y = __fdividef(1.f, 1.f + __expf(-tv[5]));
    s1.z = __fdividef(1.f, 1.f + __expf(-tv[6]));
    s1.w = __fdividef(1.f, 1.f + __expf(-tv[7]));
    __builtin_nontemporal_store(s0, (floatx4*)orow);
    __builtin_nontemporal_store(s1, (floatx4*)orow + 1);
  }
}

extern "C" void kernel_launch(void* const* d_in, const int* in_sizes, int n_in,
                              void* d_out, int out_size, void* d_ws, size_t ws_size,
                              hipStream_t stream) {
  const int* out_nei   = (const int*)d_in[0];
  const int* in_nei    = (const int*)d_in[1];
  const int* target    = (const int*)d_in[2];
  const float* feat    = (const float*)d_in[3];
  const float* rel_emb = (const float*)d_in[4];
  const float* w       = (const float*)d_in[5];
  const float* bias    = (const float*)d_in[6];
  float* out = (float*)d_out;
  const int n_nodes = in_sizes[2];

  __half* St = (__half*)d_ws;
  __half* P  = (__half*)((char*)d_ws + ST_BYTES);

  const int nbf = (n_nodes * 8 + 255) / 256;   // 1563 fuse blocks @ N=50000
  warm_build_kernel<<<nbf + N_REL, 256, 0, stream>>>(
      out_nei, in_nei, target, rel_emb, w, bias, feat, St, P, n_nodes, nbf);
  fuse_kernel<<<nbf, 256, 0, stream>>>(out_nei, in_nei, target, feat, St, P,
                                       out, n_nodes);
}

// Round 15
// 20.699 us; speedup vs baseline: 1.1002x; 1.1002x over previous
//
#include <hip/hip_runtime.h>
#include <hip/hip_fp16.h>

#define N_REL 201   // NUM_RELS + 1 (PAD row 200 is all-zero)
#define N_TGT 200   // target_rels < 200
#define SEM 32      // SEM_DIM
#define KNEI 20     // K neighbors
#define PSTRIDE 40  // halfs per P row (80 B -> uniform spread over all 8 quad-groups)

typedef float floatx4 __attribute__((ext_vector_type(4)));

// Workspace: [0,80400) __half St[200][201]; [80400,+32160) __half P[402][40]
#define ST_BYTES 80400                 // 16-aligned (16*5025)
#define P_HALFS (2 * N_REL * PSTRIDE)  // 16080
#define P_U4 (P_HALFS * 2 / 16)        // 2010

#define EMB_STRIDE 68   // floats/row: 16B-aligned, dword-stride 17 (odd)
#define WL_STRIDE 132   // floats/row: 16B-aligned, dword-stride 33 (odd)

// ---------------------------------------------------------------------------
// Kernel 1 (vectorized): St[j][i] = emb[i]·emb[j] (fp16);
// P[dir*201+i][c] = emb[i]·W_dir_c + bias[c]/2 (fp16).
// ---------------------------------------------------------------------------
__global__ __launch_bounds__(256) void build_tables_kernel(
    const float* __restrict__ rel_emb,   // [201][64]
    const float* __restrict__ w,         // [32][128]
    const float* __restrict__ bias,      // [32]
    __half* __restrict__ St,             // [200][201] transposed
    __half* __restrict__ P)              // [402][PSTRIDE]
{
  __shared__ __align__(16) float embL[N_REL * EMB_STRIDE];
  __shared__ __align__(16) float wL[SEM * WL_STRIDE];
  const int t = threadIdx.x;
  for (int e = t; e < N_REL * 16; e += 256) {
    const int r = e >> 4, s = e & 15;
    *(float4*)&embL[r * EMB_STRIDE + s * 4] = ((const float4*)rel_emb)[e];
  }
  for (int e = t; e < SEM * 32; e += 256) {
    const int r = e >> 5, s = e & 31;
    *(float4*)&wL[r * WL_STRIDE + s * 4] = ((const float4*)w)[e];
  }
  __syncthreads();

  const int i = blockIdx.x;  // 0..200 (idx dimension)
  const float4* __restrict__ ri = (const float4*)&embL[i * EMB_STRIDE];
  for (int jj = t; jj < N_TGT; jj += 256) {
    const float4* __restrict__ rj = (const float4*)&embL[jj * EMB_STRIDE];
    float acc = 0.f;
#pragma unroll
    for (int d = 0; d < 16; ++d) {
      const float4 a = ri[d], b = rj[d];
      acc = fmaf(a.x, b.x, acc);
      acc = fmaf(a.y, b.y, acc);
      acc = fmaf(a.z, b.z, acc);
      acc = fmaf(a.w, b.w, acc);
    }
    St[jj * N_REL + i] = __float2half(acc);
  }
  if (t < 64) {
    const int hh = t >> 5, jj = t & 31;
    const float4* __restrict__ rw = (const float4*)&wL[jj * WL_STRIDE + hh * 64];
    float acc = 0.5f * bias[jj];
#pragma unroll
    for (int d = 0; d < 16; ++d) {
      const float4 a = ri[d], b = rw[d];
      acc = fmaf(a.x, b.x, acc);
      acc = fmaf(a.y, b.y, acc);
      acc = fmaf(a.z, b.z, acc);
      acc = fmaf(a.w, b.w, acc);
    }
    P[(hh * N_REL + i) * PSTRIDE + jj] = __float2half(acc);
  }
}

// ---------------------------------------------------------------------------
// Kernel 2 (session best, r13): 8 lanes/node, 256-thr blocks, 1563 blocks.
// uint4 idx loads (lane q owns k in {4q..4q+3, 16+q}); plain feat loads;
// NT stores on out only. Phase order: inputs -> P staging (hides latency)
// -> S gathers -> quad softmax -> 20 b128 LDS row-gathers -> store.
// ---------------------------------------------------------------------------
__global__ __launch_bounds__(256, 4) void fuse_kernel(
    const int* __restrict__ out_nei, const int* __restrict__ in_nei,
    const int* __restrict__ target, const float* __restrict__ feat,
    const __half* __restrict__ St, const __half* __restrict__ Pg,
    float* __restrict__ out, int n_nodes)
{
  __shared__ __align__(16) __half P_l[P_HALFS];    // 32160 B
  const int t = threadIdx.x;
  const int gid = blockIdx.x * 256 + t;
  const int n = gid >> 3;
  const int sub = t & 7;
  const int dir = sub >> 2;   // 0 = out, 1 = in
  const int q = sub & 3;      // 8-dim slice / k-chunk
  const bool active = (n < n_nodes);
  const int* __restrict__ nei = dir ? in_nei : out_nei;

  // ---- phase 1: issue all input loads (latency hides under P staging) ----
  int tgt = 0, ex = 0;
  uint4 c4 = {0, 0, 0, 0};
  floatx4 f0, f1;
  if (active) {
    tgt = target[n];
    c4 = *(const uint4*)(nei + (size_t)n * KNEI + 4 * q);
    ex = nei[(size_t)n * KNEI + 16 + q];
    if (dir == 0) {
      const floatx4* fr = (const floatx4*)(feat + (size_t)n * SEM + q * 8);
      f0 = fr[0];
      f1 = fr[1];
    }
  }

  // ---- phase 2: stage P into LDS ----
  {
    const uint4* p4 = (const uint4*)Pg;
    uint4* pl = (uint4*)P_l;
    for (int e = t; e < P_U4; e += 256) pl[e] = p4[e];
  }
  __syncthreads();
  if (!active) return;

  // ---- phase 3: S gathers (St row tgt, hot in L1/L2) ----
  const __half* __restrict__ srow = St + (size_t)tgt * N_REL;
  float ev[5];
  ev[0] = __half2float(srow[c4.x]);
  ev[1] = __half2float(srow[c4.y]);
  ev[2] = __half2float(srow[c4.z]);
  ev[3] = __half2float(srow[c4.w]);
  ev[4] = __half2float(srow[ex]);

  // ---- softmax with max-subtraction (self-neighbor scores ~ ||emb||^2) ----
  float mx = fmaxf(fmaxf(fmaxf(ev[0], ev[1]), fmaxf(ev[2], ev[3])), ev[4]);
  mx = fmaxf(mx, __shfl_xor(mx, 1, 64));
  mx = fmaxf(mx, __shfl_xor(mx, 2, 64));
  float e5[5], s = 0.f;
#pragma unroll
  for (int i = 0; i < 5; ++i) { e5[i] = __expf(ev[i] - mx); s += e5[i]; }
  s += __shfl_xor(s, 1, 64);
  s += __shfl_xor(s, 2, 64);
  const float inv = __fdividef(1.f, s);

  // ---- pack {idx | w_fp16}; all-gather within the dir quad ----
  const int ia[5] = {(int)c4.x, (int)c4.y, (int)c4.z, (int)c4.w, ex};
  unsigned int pk[20];
#pragma unroll
  for (int i = 0; i < 5; ++i) {
    const __half hw = __float2half(e5[i] * inv);
    pk[i] = ((unsigned int)ia[i] << 16) | (unsigned int)__half_as_ushort(hw);
  }
#pragma unroll
  for (int i = 0; i < 5; ++i) pk[5 + i] = __shfl_xor(pk[i], 1, 64);
#pragma unroll
  for (int i = 0; i < 10; ++i) pk[10 + i] = __shfl_xor(pk[i], 2, 64);

  // ---- aggregate 20 rows, own 8-dim slice (1 b128 per row, BW-floor) ----
  __half2 acc[4];
#pragma unroll
  for (int m = 0; m < 4; ++m) acc[m] = __float2half2_rn(0.f);
  const int dbase = dir * (N_REL * PSTRIDE) + q * 8;
#pragma unroll
  for (int i = 0; i < 20; ++i) {
    const int idx = (int)(pk[i] >> 16);
    const unsigned int lo = pk[i] & 0xFFFFu;
    const unsigned int dd = lo | (lo << 16);
    const __half2 a2 = *(const __half2*)&dd;
    const uint4 qv = *(const uint4*)&P_l[dbase + idx * PSTRIDE];
    acc[0] = __hfma2(a2, *(const __half2*)&qv.x, acc[0]);
    acc[1] = __hfma2(a2, *(const __half2*)&qv.y, acc[1]);
    acc[2] = __hfma2(a2, *(const __half2*)&qv.z, acc[2]);
    acc[3] = __hfma2(a2, *(const __half2*)&qv.w, acc[3]);
  }

  // ---- combine directions: partner lane = lane ^ 4 ----
#pragma unroll
  for (int m = 0; m < 4; ++m) {
    const unsigned int u = *(const unsigned int*)&acc[m];
    const unsigned int v = __shfl_xor(u, 4, 64);
    acc[m] = __hadd2(acc[m], *(const __half2*)&v);
  }

  // ---- write: lanes 0-3 -> feat slice, lanes 4-7 -> sigmoid slice (NT) ----
  float* orow = out + (size_t)n * 64 + sub * 8;
  if (dir == 0) {
    __builtin_nontemporal_store(f0, (floatx4*)orow);
    __builtin_nontemporal_store(f1, (floatx4*)orow + 1);
  } else {
    float tv[8];
#pragma unroll
    for (int m = 0; m < 4; ++m) {
      tv[2 * m]     = __low2float(acc[m]);
      tv[2 * m + 1] = __high2float(acc[m]);
    }
    floatx4 s0, s1;
    s0.x = __fdividef(1.f, 1.f + __expf(-tv[0]));
    s0.y = __fdividef(1.f, 1.f + __expf(-tv[1]));
    s0.z = __fdividef(1.f, 1.f + __expf(-tv[2]));
    s0.w = __fdividef(1.f, 1.f + __expf(-tv[3]));
    s1.x = __fdividef(1.f, 1.f + __expf(-tv[4]));
    s1.y = __fdividef(1.f, 1.f + __expf(-tv[5]));
    s1.z = __fdividef(1.f, 1.f + __expf(-tv[6]));
    s1.w = __fdividef(1.f, 1.f + __expf(-tv[7]));
    __builtin_nontemporal_store(s0, (floatx4*)orow);
    __builtin_nontemporal_store(s1, (floatx4*)orow + 1);
  }
}

extern "C" void kernel_launch(void* const* d_in, const int* in_sizes, int n_in,
                              void* d_out, int out_size, void* d_ws, size_t ws_size,
                              hipStream_t stream) {
  const int* out_nei   = (const int*)d_in[0];
  const int* in_nei    = (const int*)d_in[1];
  const int* target    = (const int*)d_in[2];
  const float* feat    = (const float*)d_in[3];
  const float* rel_emb = (const float*)d_in[4];
  const float* w       = (const float*)d_in[5];
  const float* bias    = (const float*)d_in[6];
  float* out = (float*)d_out;
  const int n_nodes = in_sizes[2];

  __half* St = (__half*)d_ws;
  __half* P  = (__half*)((char*)d_ws + ST_BYTES);

  build_tables_kernel<<<N_REL, 256, 0, stream>>>(rel_emb, w, bias, St, P);
  const int total_threads = n_nodes * 8;
  const int nb = (total_threads + 255) / 256;   // 1563 blocks @ N=50000
  fuse_kernel<<<nb, 256, 0, stream>>>(out_nei, in_nei, target, feat, St, P,
                                      out, n_nodes);
}